// Round 1
// baseline (685.832 us; speedup 1.0000x reference)
//
#include <hip/hip_runtime.h>
#include <cstdint>
#include <cstddef>

#define H_DIM 2048
#define I_DIM 1024
#define E_NUM 16
#define T_NUM 2048

typedef float floatx4 __attribute__((ext_vector_type(4)));
using short8 = __attribute__((ext_vector_type(8))) short;

__device__ __forceinline__ short f2bf(float f) {
  unsigned u = __float_as_uint(f);
  u += 0x7FFFu + ((u >> 16) & 1u);
  return (short)(u >> 16);
}

// async global->LDS, 16B per lane. LDS dest must be wave-uniform base + lane*16.
__device__ __forceinline__ void cp16(const void* g, void* l) {
  __builtin_amdgcn_global_load_lds(
      (__attribute__((address_space(1))) void*)(void*)g,
      (__attribute__((address_space(3))) void*)l, 16, 0, 0);
}

// ---------------- transpose + fp32->bf16: in[e][R][C] -> out[e][C][R] ----------------
__global__ __launch_bounds__(256) void transpose_bf16_kernel(
    const float* __restrict__ in, short* __restrict__ out, int R, int C) {
  __shared__ short tile[64 * 68];  // pad 68: col reads land 2 lanes/bank (free)
  int e = blockIdx.z;
  int r0 = blockIdx.y * 64, c0 = blockIdx.x * 64;
  int tid = threadIdx.x;
  int qr = tid >> 4;          // 0..15
  int qc = (tid & 15) * 4;    // 0..60
  const float* src = in + ((size_t)e * R + r0) * C + c0;
#pragma unroll
  for (int it = 0; it < 4; ++it) {
    int r = it * 16 + qr;
    float4 v = *(const float4*)(src + (size_t)r * C + qc);
    short4 s4;
    s4.x = f2bf(v.x); s4.y = f2bf(v.y); s4.z = f2bf(v.z); s4.w = f2bf(v.w);
    *(short4*)&tile[r * 68 + qc] = s4;
  }
  __syncthreads();
  short* dst = out + ((size_t)e * C + c0) * R + r0;
#pragma unroll
  for (int it = 0; it < 4; ++it) {
    int c = it * 16 + qr;     // output row (over C)
    short4 s4;
    s4.x = tile[(qc + 0) * 68 + c];
    s4.y = tile[(qc + 1) * 68 + c];
    s4.z = tile[(qc + 2) * 68 + c];
    s4.w = tile[(qc + 3) * 68 + c];
    *(short4*)(dst + (size_t)c * R + qc) = s4;
  }
}

// ---------------- router: logits -> softmax -> top4 -> expert buckets; x -> bf16 ----------------
__global__ __launch_bounds__(256) void router_kernel(
    const float* __restrict__ x, const float* __restrict__ wr,
    short* __restrict__ xbf, int* __restrict__ counts,
    int* __restrict__ tokl, float* __restrict__ wgtl) {
  int t = blockIdx.x;
  int tid = threadIdx.x;
  const float* xr = x + (size_t)t * H_DIM;
  float acc[E_NUM];
#pragma unroll
  for (int e = 0; e < 16; ++e) acc[e] = 0.f;
  for (int h = tid; h < H_DIM; h += 256) {
    float xv = xr[h];
    xbf[(size_t)t * H_DIM + h] = f2bf(xv);
    const float4* w4 = (const float4*)(wr + h * 16);
#pragma unroll
    for (int j = 0; j < 4; ++j) {
      float4 wv = w4[j];
      acc[j * 4 + 0] += xv * wv.x;
      acc[j * 4 + 1] += xv * wv.y;
      acc[j * 4 + 2] += xv * wv.z;
      acc[j * 4 + 3] += xv * wv.w;
    }
  }
#pragma unroll
  for (int off = 32; off >= 1; off >>= 1)
#pragma unroll
    for (int e = 0; e < 16; ++e) acc[e] += __shfl_down(acc[e], off);
  __shared__ float red[4][16];
  int wv_ = tid >> 6, ln = tid & 63;
  if (ln == 0)
#pragma unroll
    for (int e = 0; e < 16; ++e) red[wv_][e] = acc[e];
  __syncthreads();
  if (tid < 64) {
    float logit = -1e30f;
    if (ln < 16) logit = red[0][ln] + red[1][ln] + red[2][ln] + red[3][ln];
    float m = logit;
#pragma unroll
    for (int off = 8; off >= 1; off >>= 1) m = fmaxf(m, __shfl_xor(m, off));
    float p = __expf(logit - m);  // softmax denom cancels in top-4 renorm
    float myp = p;
    float bestv[4]; int besti[4];
#pragma unroll
    for (int kk = 0; kk < 4; ++kk) {
      float cv = myp; int ci = ln;
#pragma unroll
      for (int off = 8; off >= 1; off >>= 1) {
        float ov = __shfl_xor(cv, off);
        int oi = __shfl_xor(ci, off);
        if (ov > cv || (ov == cv && oi < ci)) { cv = ov; ci = oi; }
      }
      bestv[kk] = cv; besti[kk] = ci;
      if (ln == ci) myp = -1.f;
    }
    float s4 = bestv[0] + bestv[1] + bestv[2] + bestv[3];
    if (ln < 4) {
      int e = besti[ln];
      int slot = atomicAdd(&counts[e], 1);
      tokl[e * T_NUM + slot] = t * 4 + ln;   // packed: token*4 + k-slot
      wgtl[e * T_NUM + slot] = bestv[ln] / s4;
    }
  }
}

// ---------------- fused gate+up GEMM + SiLU epilogue ----------------
// A = gathered x rows (bf16), Bg/Bu = wT[e] rows (K-major), 128x128 tile, BK=32.
__global__ __launch_bounds__(256, 2) void gateup_kernel(
    const short* __restrict__ xbf, const short* __restrict__ wgT,
    const short* __restrict__ wuT, const int* __restrict__ counts,
    const int* __restrict__ tokl, const float* __restrict__ wgtl,
    short* __restrict__ act) {
  int e = blockIdx.z, mt = blockIdx.y, nt = blockIdx.x;
  int cnt = counts[e];
  int m0 = mt * 128;
  if (m0 >= cnt) return;
  int n0 = nt * 128;
  __shared__ short Al[128 * 32];
  __shared__ short Bgl[128 * 32];
  __shared__ short Bul[128 * 32];
  __shared__ int s_tok[128];
  __shared__ float s_w[128];
  int tid = threadIdx.x;
  if (tid < 128) {
    int idx = m0 + tid;
    int ok = idx < cnt;
    s_tok[tid] = ok ? tokl[e * T_NUM + idx] : 0;
    s_w[tid] = ok ? wgtl[e * T_NUM + idx] : 0.f;
  }
  __syncthreads();
  const short* aptr[2]; const short* gptr[2]; const short* uptr[2];
#pragma unroll
  for (int q = 0; q < 2; ++q) {
    int c = q * 256 + tid;
    int r = c >> 2, sub = c & 3;
    int tk = s_tok[r] >> 2;
    aptr[q] = xbf + (size_t)tk * H_DIM + sub * 8;
    gptr[q] = wgT + ((size_t)e * I_DIM + n0 + r) * H_DIM + sub * 8;
    uptr[q] = wuT + ((size_t)e * I_DIM + n0 + r) * H_DIM + sub * 8;
  }
  int wv = tid >> 6, ln = tid & 63;
  int msub = (wv & 1) * 64, nsub = (wv >> 1) * 64;
  int a_base = (msub + (ln & 15)) * 32 + (ln >> 4) * 8;
  int b_base = (nsub + (ln & 15)) * 32 + (ln >> 4) * 8;
  floatx4 accg[16], accu[16];
  floatx4 zero = {0.f, 0.f, 0.f, 0.f};
#pragma unroll
  for (int i = 0; i < 16; ++i) { accg[i] = zero; accu[i] = zero; }
  for (int k0 = 0; k0 < H_DIM; k0 += 32) {
    __syncthreads();
#pragma unroll
    for (int q = 0; q < 2; ++q) {
      int off8 = q * 2048 + wv * 512;  // wave-uniform LDS chunk (shorts)
      cp16(aptr[q] + k0, Al + off8);
      cp16(gptr[q] + k0, Bgl + off8);
      cp16(uptr[q] + k0, Bul + off8);
    }
    __syncthreads();
    short8 a[4], bg[4], bu[4];
#pragma unroll
    for (int i = 0; i < 4; ++i) {
      a[i]  = *(const short8*)(Al + a_base + i * 16 * 32);
      bg[i] = *(const short8*)(Bgl + b_base + i * 16 * 32);
      bu[i] = *(const short8*)(Bul + b_base + i * 16 * 32);
    }
#pragma unroll
    for (int i = 0; i < 4; ++i)
#pragma unroll
      for (int j = 0; j < 4; ++j) {
        accg[i * 4 + j] = __builtin_amdgcn_mfma_f32_16x16x32_bf16(a[i], bg[j], accg[i * 4 + j], 0, 0, 0);
        accu[i * 4 + j] = __builtin_amdgcn_mfma_f32_16x16x32_bf16(a[i], bu[j], accu[i * 4 + j], 0, 0, 0);
      }
  }
  int crem = cnt - m0;
#pragma unroll
  for (int i = 0; i < 4; ++i)
#pragma unroll
    for (int j = 0; j < 4; ++j) {
      floatx4 g = accg[i * 4 + j], u = accu[i * 4 + j];
      int col = n0 + nsub + j * 16 + (ln & 15);
#pragma unroll
      for (int r = 0; r < 4; ++r) {
        int rl = msub + i * 16 + (ln >> 4) * 4 + r;
        if (rl < crem) {
          float gv = g[r];
          float av = gv / (1.f + __expf(-gv)) * u[r] * s_w[rl];
          act[(size_t)s_tok[rl] * I_DIM + col] = f2bf(av);
        }
      }
    }
}

// ---------------- down GEMM + atomic combine ----------------
__global__ __launch_bounds__(256, 2) void down_kernel(
    const short* __restrict__ act, const short* __restrict__ wdT,
    const int* __restrict__ counts, const int* __restrict__ tokl,
    float* __restrict__ out) {
  int e = blockIdx.z, mt = blockIdx.y, nt = blockIdx.x;
  int cnt = counts[e];
  int m0 = mt * 128;
  if (m0 >= cnt) return;
  int n0 = nt * 128;
  __shared__ short Al[128 * 32];
  __shared__ short Bl[128 * 32];
  __shared__ int s_tok[128];
  int tid = threadIdx.x;
  if (tid < 128) {
    int idx = m0 + tid;
    s_tok[tid] = (idx < cnt) ? tokl[e * T_NUM + idx] : 0;
  }
  __syncthreads();
  const short* aptr[2]; const short* bptr[2];
#pragma unroll
  for (int q = 0; q < 2; ++q) {
    int c = q * 256 + tid;
    int r = c >> 2, sub = c & 3;
    aptr[q] = act + (size_t)s_tok[r] * I_DIM + sub * 8;
    bptr[q] = wdT + ((size_t)e * H_DIM + n0 + r) * I_DIM + sub * 8;
  }
  int wv = tid >> 6, ln = tid & 63;
  int msub = (wv & 1) * 64, nsub = (wv >> 1) * 64;
  int a_base = (msub + (ln & 15)) * 32 + (ln >> 4) * 8;
  int b_base = (nsub + (ln & 15)) * 32 + (ln >> 4) * 8;
  floatx4 acc[16];
  floatx4 zero = {0.f, 0.f, 0.f, 0.f};
#pragma unroll
  for (int i = 0; i < 16; ++i) acc[i] = zero;
  for (int k0 = 0; k0 < I_DIM; k0 += 32) {
    __syncthreads();
#pragma unroll
    for (int q = 0; q < 2; ++q) {
      int off8 = q * 2048 + wv * 512;
      cp16(aptr[q] + k0, Al + off8);
      cp16(bptr[q] + k0, Bl + off8);
    }
    __syncthreads();
    short8 a[4], b[4];
#pragma unroll
    for (int i = 0; i < 4; ++i) {
      a[i] = *(const short8*)(Al + a_base + i * 16 * 32);
      b[i] = *(const short8*)(Bl + b_base + i * 16 * 32);
    }
#pragma unroll
    for (int i = 0; i < 4; ++i)
#pragma unroll
      for (int j = 0; j < 4; ++j)
        acc[i * 4 + j] = __builtin_amdgcn_mfma_f32_16x16x32_bf16(a[i], b[j], acc[i * 4 + j], 0, 0, 0);
  }
  int crem = cnt - m0;
#pragma unroll
  for (int i = 0; i < 4; ++i)
#pragma unroll
    for (int j = 0; j < 4; ++j) {
      int col = n0 + nsub + j * 16 + (ln & 15);
#pragma unroll
      for (int r = 0; r < 4; ++r) {
        int rl = msub + i * 16 + (ln >> 4) * 4 + r;
        if (rl < crem) {
          int t = s_tok[rl] >> 2;
          unsafeAtomicAdd(&out[(size_t)t * H_DIM + col], acc[i * 4 + j][r]);
        }
      }
    }
}

extern "C" void kernel_launch(void* const* d_in, const int* in_sizes, int n_in,
                              void* d_out, int out_size, void* d_ws, size_t ws_size,
                              hipStream_t stream) {
  const float* x  = (const float*)d_in[0];
  const float* wr = (const float*)d_in[1];
  const float* wg = (const float*)d_in[2];
  const float* wu = (const float*)d_in[3];
  const float* wd = (const float*)d_in[4];
  float* out = (float*)d_out;

  char* ws = (char*)d_ws;
  const size_t WT_SZ = (size_t)E_NUM * I_DIM * H_DIM * 2;  // 64 MiB each
  size_t off = 0;
  short* wgT = (short*)(ws + off); off += WT_SZ;
  short* wuT = (short*)(ws + off); off += WT_SZ;
  short* wdT = (short*)(ws + off); off += WT_SZ;
  short* xbf = (short*)(ws + off); off += (size_t)T_NUM * H_DIM * 2;
  short* act = (short*)(ws + off); off += (size_t)T_NUM * 4 * I_DIM * 2;
  int* counts = (int*)(ws + off); off += 256;
  int* tokl = (int*)(ws + off); off += (size_t)E_NUM * T_NUM * 4;
  float* wgtl = (float*)(ws + off); off += (size_t)E_NUM * T_NUM * 4;

  hipMemsetAsync(d_out, 0, (size_t)out_size * sizeof(float), stream);
  if (off > ws_size) return;  // ws too small -> zeros out (diagnostic: absmax == 1.109)
  hipMemsetAsync(counts, 0, 256, stream);

  dim3 blk(256);
  transpose_bf16_kernel<<<dim3(I_DIM / 64, H_DIM / 64, E_NUM), blk, 0, stream>>>(wg, wgT, H_DIM, I_DIM);
  transpose_bf16_kernel<<<dim3(I_DIM / 64, H_DIM / 64, E_NUM), blk, 0, stream>>>(wu, wuT, H_DIM, I_DIM);
  transpose_bf16_kernel<<<dim3(H_DIM / 64, I_DIM / 64, E_NUM), blk, 0, stream>>>(wd, wdT, I_DIM, H_DIM);
  router_kernel<<<dim3(T_NUM), blk, 0, stream>>>(x, wr, xbf, counts, tokl, wgtl);
  gateup_kernel<<<dim3(I_DIM / 128, T_NUM / 128, E_NUM), blk, 0, stream>>>(xbf, wgT, wuT, counts, tokl, wgtl, act);
  down_kernel<<<dim3(H_DIM / 128, T_NUM / 128, E_NUM), blk, 0, stream>>>(act, wdT, counts, tokl, out);
}

// Round 2
// 678.145 us; speedup vs baseline: 1.0113x; 1.0113x over previous
//
#include <hip/hip_runtime.h>
#include <cstdint>
#include <cstddef>

#define H_DIM 2048
#define I_DIM 1024
#define E_NUM 16
#define T_NUM 2048
#define BK 64

typedef float floatx4 __attribute__((ext_vector_type(4)));
using short8 = __attribute__((ext_vector_type(8))) short;

__device__ __forceinline__ short f2bf(float f) {
  unsigned u = __float_as_uint(f);
  u += 0x7FFFu + ((u >> 16) & 1u);
  return (short)(u >> 16);
}

// async global->LDS, 16B per lane. LDS dest must be wave-uniform base + lane*16.
__device__ __forceinline__ void cp16(const void* g, void* l) {
  __builtin_amdgcn_global_load_lds(
      (__attribute__((address_space(1))) void*)(void*)g,
      (__attribute__((address_space(3))) void*)l, 16, 0, 0);
}

// ---------------- transpose + fp32->bf16: in[e][R][C] -> out[e][C][R] ----------------
// z < zsplit: first src; else second (gate/up merged).
__global__ __launch_bounds__(256) void transpose_bf16_kernel(
    const float* __restrict__ inA, const float* __restrict__ inB,
    short* __restrict__ outA, short* __restrict__ outB, int R, int C, int zsplit) {
  __shared__ short tile[64 * 68];
  int z = blockIdx.z;
  const float* in = (z < zsplit) ? inA : inB;
  short* out = (z < zsplit) ? outA : outB;
  int e = (z < zsplit) ? z : z - zsplit;
  int r0 = blockIdx.y * 64, c0 = blockIdx.x * 64;
  int tid = threadIdx.x;
  int qr = tid >> 4;
  int qc = (tid & 15) * 4;
  const float* src = in + ((size_t)e * R + r0) * C + c0;
#pragma unroll
  for (int it = 0; it < 4; ++it) {
    int r = it * 16 + qr;
    float4 v = *(const float4*)(src + (size_t)r * C + qc);
    short4 s4;
    s4.x = f2bf(v.x); s4.y = f2bf(v.y); s4.z = f2bf(v.z); s4.w = f2bf(v.w);
    *(short4*)&tile[r * 68 + qc] = s4;
  }
  __syncthreads();
  short* dst = out + ((size_t)e * C + c0) * R + r0;
#pragma unroll
  for (int it = 0; it < 4; ++it) {
    int c = it * 16 + qr;
    short4 s4;
    s4.x = tile[(qc + 0) * 68 + c];
    s4.y = tile[(qc + 1) * 68 + c];
    s4.z = tile[(qc + 2) * 68 + c];
    s4.w = tile[(qc + 3) * 68 + c];
    *(short4*)(dst + (size_t)c * R + qc) = s4;
  }
}

// ---------------- router ----------------
__global__ __launch_bounds__(256) void router_kernel(
    const float* __restrict__ x, const float* __restrict__ wr,
    short* __restrict__ xbf, int* __restrict__ counts,
    int* __restrict__ tokl, float* __restrict__ wgtl) {
  int t = blockIdx.x;
  int tid = threadIdx.x;
  const float* xr = x + (size_t)t * H_DIM;
  float acc[E_NUM];
#pragma unroll
  for (int e = 0; e < 16; ++e) acc[e] = 0.f;
  for (int h = tid; h < H_DIM; h += 256) {
    float xv = xr[h];
    xbf[(size_t)t * H_DIM + h] = f2bf(xv);
    const float4* w4 = (const float4*)(wr + h * 16);
#pragma unroll
    for (int j = 0; j < 4; ++j) {
      float4 wv = w4[j];
      acc[j * 4 + 0] += xv * wv.x;
      acc[j * 4 + 1] += xv * wv.y;
      acc[j * 4 + 2] += xv * wv.z;
      acc[j * 4 + 3] += xv * wv.w;
    }
  }
#pragma unroll
  for (int off = 32; off >= 1; off >>= 1)
#pragma unroll
    for (int e = 0; e < 16; ++e) acc[e] += __shfl_down(acc[e], off);
  __shared__ float red[4][16];
  int wv_ = tid >> 6, ln = tid & 63;
  if (ln == 0)
#pragma unroll
    for (int e = 0; e < 16; ++e) red[wv_][e] = acc[e];
  __syncthreads();
  if (tid < 64) {
    float logit = -1e30f;
    if (ln < 16) logit = red[0][ln] + red[1][ln] + red[2][ln] + red[3][ln];
    float m = logit;
#pragma unroll
    for (int off = 8; off >= 1; off >>= 1) m = fmaxf(m, __shfl_xor(m, off));
    float p = __expf(logit - m);
    float myp = p;
    float bestv[4]; int besti[4];
#pragma unroll
    for (int kk = 0; kk < 4; ++kk) {
      float cv = myp; int ci = ln;
#pragma unroll
      for (int off = 8; off >= 1; off >>= 1) {
        float ov = __shfl_xor(cv, off);
        int oi = __shfl_xor(ci, off);
        if (ov > cv || (ov == cv && oi < ci)) { cv = ov; ci = oi; }
      }
      bestv[kk] = cv; besti[kk] = ci;
      if (ln == ci) myp = -1.f;
    }
    float s4 = bestv[0] + bestv[1] + bestv[2] + bestv[3];
    if (ln < 4) {
      int e = besti[ln];
      int slot = atomicAdd(&counts[e], 1);
      tokl[e * T_NUM + slot] = t * 4 + ln;
      wgtl[e * T_NUM + slot] = bestv[ln] / s4;
    }
  }
}

// ---------------- tile scheduler: dense (e, mtile) list ----------------
__global__ void sched_kernel(const int* __restrict__ counts, int* __restrict__ desc,
                             int* __restrict__ ntiles) {
  if (threadIdx.x == 0 && blockIdx.x == 0) {
    int idx = 0;
    for (int e = 0; e < E_NUM; ++e) {
      int nt = (counts[e] + 127) >> 7;
      for (int m = 0; m < nt; ++m) desc[idx++] = e | (m << 8);
    }
    ntiles[0] = idx;
  }
}

// ---------------- fused gate+up GEMM + SiLU epilogue (BK=64, XOR swizzle, persistent) ----------------
__global__ __launch_bounds__(256, 2) void gateup_kernel(
    const short* __restrict__ xbf, const short* __restrict__ wgT,
    const short* __restrict__ wuT, const int* __restrict__ counts,
    const int* __restrict__ tokl, const float* __restrict__ wgtl,
    const int* __restrict__ desc, const int* __restrict__ ntiles,
    short* __restrict__ act) {
  __shared__ short Al[128 * BK];
  __shared__ short Bgl[128 * BK];
  __shared__ short Bul[128 * BK];
  __shared__ int s_tok[128];
  __shared__ float s_w[128];
  int tid = threadIdx.x;
  int wv = tid >> 6, ln = tid & 63;
  int msub = (wv & 1) * 64, nsub = (wv >> 1) * 64;
  int lm = ln & 15, kq = ln >> 4;
  int total = ntiles[0] * 8;
  for (int w = blockIdx.x; w < total; w += gridDim.x) {
    int nt = w & 7;
    int d = desc[w >> 3];
    int e = d & 0xFF, m0 = (d >> 8) * 128, n0 = nt * 128;
    int cnt = counts[e];
    __syncthreads();  // protect s_tok/s_w from previous tile's epilogue
    if (tid < 128) {
      int idx = m0 + tid;
      int ok = idx < cnt;
      s_tok[tid] = ok ? tokl[e * T_NUM + idx] : 0;
      s_w[tid] = ok ? wgtl[e * T_NUM + idx] : 0.f;
    }
    __syncthreads();
    // staging sources: thread handles 4 chunks per matrix; swizzle on source side
    const short* ab[4]; const short* gb[4]; const short* ub[4];
#pragma unroll
    for (int q = 0; q < 4; ++q) {
      int f = q * 256 + tid;
      int row = f >> 3;
      int c = (f & 7) ^ (row & 7);
      ab[q] = xbf + (size_t)(s_tok[row] >> 2) * H_DIM + c * 8;
      gb[q] = wgT + ((size_t)e * I_DIM + n0 + row) * H_DIM + c * 8;
      ub[q] = wuT + ((size_t)e * I_DIM + n0 + row) * H_DIM + c * 8;
    }
    floatx4 accg[16], accu[16];
    floatx4 zero = {0.f, 0.f, 0.f, 0.f};
#pragma unroll
    for (int i = 0; i < 16; ++i) { accg[i] = zero; accu[i] = zero; }
    for (int k0 = 0; k0 < H_DIM; k0 += BK) {
      __syncthreads();
#pragma unroll
      for (int q = 0; q < 4; ++q) {
        int l8 = (q * 256 + tid) * 8;
        cp16(ab[q] + k0, Al + l8);
        cp16(gb[q] + k0, Bgl + l8);
        cp16(ub[q] + k0, Bul + l8);
      }
      __syncthreads();
#pragma unroll
      for (int s = 0; s < 2; ++s) {
        int posA = ((s * 4 + kq) ^ (lm & 7)) * 8;
        short8 a[4], bg[4], bu[4];
#pragma unroll
        for (int i = 0; i < 4; ++i) {
          int m = msub + i * 16 + lm;
          a[i] = *(const short8*)(Al + m * BK + posA);
        }
#pragma unroll
        for (int j = 0; j < 4; ++j) {
          int n = nsub + j * 16 + lm;
          bg[j] = *(const short8*)(Bgl + n * BK + posA);
          bu[j] = *(const short8*)(Bul + n * BK + posA);
        }
#pragma unroll
        for (int i = 0; i < 4; ++i)
#pragma unroll
          for (int j = 0; j < 4; ++j) {
            accg[i * 4 + j] = __builtin_amdgcn_mfma_f32_16x16x32_bf16(a[i], bg[j], accg[i * 4 + j], 0, 0, 0);
            accu[i * 4 + j] = __builtin_amdgcn_mfma_f32_16x16x32_bf16(a[i], bu[j], accu[i * 4 + j], 0, 0, 0);
          }
      }
    }
    int crem = cnt - m0;
#pragma unroll
    for (int i = 0; i < 4; ++i)
#pragma unroll
      for (int j = 0; j < 4; ++j) {
        floatx4 g = accg[i * 4 + j], u = accu[i * 4 + j];
        int col = n0 + nsub + j * 16 + lm;
#pragma unroll
        for (int r = 0; r < 4; ++r) {
          int rl = msub + i * 16 + kq * 4 + r;
          if (rl < crem) {
            float gv = g[r];
            float av = gv / (1.f + __expf(-gv)) * u[r] * s_w[rl];
            act[(size_t)s_tok[rl] * I_DIM + col] = f2bf(av);
          }
        }
      }
  }
}

// ---------------- down GEMM + atomic combine (BK=64, XOR swizzle, persistent) ----------------
__global__ __launch_bounds__(256, 2) void down_kernel(
    const short* __restrict__ act, const short* __restrict__ wdT,
    const int* __restrict__ counts, const int* __restrict__ tokl,
    const int* __restrict__ desc, const int* __restrict__ ntiles,
    float* __restrict__ out) {
  __shared__ short Al[128 * BK];
  __shared__ short Bl[128 * BK];
  __shared__ int s_tok[128];
  int tid = threadIdx.x;
  int wv = tid >> 6, ln = tid & 63;
  int msub = (wv & 1) * 64, nsub = (wv >> 1) * 64;
  int lm = ln & 15, kq = ln >> 4;
  int total = ntiles[0] * 16;
  for (int w = blockIdx.x; w < total; w += gridDim.x) {
    int nt = w & 15;
    int d = desc[w >> 4];
    int e = d & 0xFF, m0 = (d >> 8) * 128, n0 = nt * 128;
    int cnt = counts[e];
    __syncthreads();
    if (tid < 128) {
      int idx = m0 + tid;
      s_tok[tid] = (idx < cnt) ? tokl[e * T_NUM + idx] : 0;
    }
    __syncthreads();
    const short* ab[4]; const short* bb[4];
#pragma unroll
    for (int q = 0; q < 4; ++q) {
      int f = q * 256 + tid;
      int row = f >> 3;
      int c = (f & 7) ^ (row & 7);
      ab[q] = act + (size_t)s_tok[row] * I_DIM + c * 8;
      bb[q] = wdT + ((size_t)e * H_DIM + n0 + row) * I_DIM + c * 8;
    }
    floatx4 acc[16];
    floatx4 zero = {0.f, 0.f, 0.f, 0.f};
#pragma unroll
    for (int i = 0; i < 16; ++i) acc[i] = zero;
    for (int k0 = 0; k0 < I_DIM; k0 += BK) {
      __syncthreads();
#pragma unroll
      for (int q = 0; q < 4; ++q) {
        int l8 = (q * 256 + tid) * 8;
        cp16(ab[q] + k0, Al + l8);
        cp16(bb[q] + k0, Bl + l8);
      }
      __syncthreads();
#pragma unroll
      for (int s = 0; s < 2; ++s) {
        int posA = ((s * 4 + kq) ^ (lm & 7)) * 8;
        short8 a[4], b[4];
#pragma unroll
        for (int i = 0; i < 4; ++i) a[i] = *(const short8*)(Al + (msub + i * 16 + lm) * BK + posA);
#pragma unroll
        for (int j = 0; j < 4; ++j) b[j] = *(const short8*)(Bl + (nsub + j * 16 + lm) * BK + posA);
#pragma unroll
        for (int i = 0; i < 4; ++i)
#pragma unroll
          for (int j = 0; j < 4; ++j)
            acc[i * 4 + j] = __builtin_amdgcn_mfma_f32_16x16x32_bf16(a[i], b[j], acc[i * 4 + j], 0, 0, 0);
      }
    }
    int crem = cnt - m0;
#pragma unroll
    for (int i = 0; i < 4; ++i)
#pragma unroll
      for (int j = 0; j < 4; ++j) {
        int col = n0 + nsub + j * 16 + lm;
#pragma unroll
        for (int r = 0; r < 4; ++r) {
          int rl = msub + i * 16 + kq * 4 + r;
          if (rl < crem) {
            int t = s_tok[rl] >> 2;
            unsafeAtomicAdd(&out[(size_t)t * H_DIM + col], acc[i * 4 + j][r]);
          }
        }
      }
  }
}

extern "C" void kernel_launch(void* const* d_in, const int* in_sizes, int n_in,
                              void* d_out, int out_size, void* d_ws, size_t ws_size,
                              hipStream_t stream) {
  const float* x  = (const float*)d_in[0];
  const float* wr = (const float*)d_in[1];
  const float* wg = (const float*)d_in[2];
  const float* wu = (const float*)d_in[3];
  const float* wd = (const float*)d_in[4];
  float* out = (float*)d_out;

  char* ws = (char*)d_ws;
  const size_t WT_SZ = (size_t)E_NUM * I_DIM * H_DIM * 2;
  size_t off = 0;
  short* wgT = (short*)(ws + off); off += WT_SZ;
  short* wuT = (short*)(ws + off); off += WT_SZ;
  short* wdT = (short*)(ws + off); off += WT_SZ;
  short* xbf = (short*)(ws + off); off += (size_t)T_NUM * H_DIM * 2;
  short* act = (short*)(ws + off); off += (size_t)T_NUM * 4 * I_DIM * 2;
  int* counts = (int*)(ws + off); off += 256;
  int* tokl = (int*)(ws + off); off += (size_t)E_NUM * T_NUM * 4;
  float* wgtl = (float*)(ws + off); off += (size_t)E_NUM * T_NUM * 4;
  int* desc = (int*)(ws + off); off += 256 * 4;
  int* ntiles = (int*)(ws + off); off += 64;

  hipMemsetAsync(d_out, 0, (size_t)out_size * sizeof(float), stream);
  if (off > ws_size) return;
  hipMemsetAsync(counts, 0, 256, stream);

  dim3 blk(256);
  transpose_bf16_kernel<<<dim3(I_DIM / 64, H_DIM / 64, 2 * E_NUM), blk, 0, stream>>>(
      wg, wu, wgT, wuT, H_DIM, I_DIM, E_NUM);
  transpose_bf16_kernel<<<dim3(H_DIM / 64, I_DIM / 64, E_NUM), blk, 0, stream>>>(
      wd, wd, wdT, wdT, I_DIM, H_DIM, E_NUM);
  router_kernel<<<dim3(T_NUM), blk, 0, stream>>>(x, wr, xbf, counts, tokl, wgtl);
  sched_kernel<<<dim3(1), dim3(64), 0, stream>>>(counts, desc, ntiles);
  gateup_kernel<<<dim3(512), blk, 0, stream>>>(xbf, wgT, wuT, counts, tokl, wgtl, desc, ntiles, act);
  down_kernel<<<dim3(512), blk, 0, stream>>>(act, wdT, counts, tokl, desc, ntiles, out);
}